// Round 3
// baseline (358.275 us; speedup 1.0000x reference)
//
#include <hip/hip_runtime.h>
#include <math.h>

#define NB 16
#define NS 4096
#define NH 768
#define NG 16
#define WRAD 15
#define WLEN 31
#define NH4 192     // NH / 4 float4 columns
#define OUTW (1 + NG)
#define NCH 32      // s-chunks per batch
#define CHUNK 128   // NS / NCH

__device__ inline float4 f4max(float4 a, float4 b) {
    return make_float4(fmaxf(a.x, b.x), fmaxf(a.y, b.y), fmaxf(a.z, b.z), fmaxf(a.w, b.w));
}
__device__ inline float4 f4add(float4 a, float4 b) {
    return make_float4(a.x + b.x, a.y + b.y, a.z + b.z, a.w + b.w);
}
__device__ inline float f4dot(float4 a, float4 b) {
    return a.x * b.x + a.y * b.y + a.z * b.z + a.w * b.w;
}

// Block reduce (blockDim.x == 192): pad LDS to 256, power-of-2 tree.
// Kept bit-identical to previous rounds so absmax stays 0.0.
__device__ inline float block_reduce_192(float v, float* sbuf) {
    int tid = threadIdx.x;
    sbuf[tid] = v;
    if (tid < 64) sbuf[192 + tid] = 0.0f;
    __syncthreads();
    for (int off = 128; off > 0; off >>= 1) {
        if (tid < off) sbuf[tid] += sbuf[tid + off];
        __syncthreads();
    }
    float r = sbuf[0];
    __syncthreads();
    return r;
}

// Per-batch completion counters for the fused last-block cls reduction.
// Zero-initialized at module load; the winning block re-arms its slot to 0
// before anyone else can observe it, so graph replays start clean.
__device__ int g_cnt[NB];

// ---------------------------------------------------------------------------
// Single-launch fused kernel:
//   blocks [0, NB*NCH)              masked text partials (compacted loop)
//   last finisher per batch         cls reduction for that batch (no 2nd launch)
//   blocks [NB*NCH, NB*NCH+NB*NG)   gap scores
// block = 192 threads; thread t owns float4 column t.
// No spin-waits anywhere: the last-block pattern cannot deadlock regardless
// of dispatch order or co-residency.
// ---------------------------------------------------------------------------
__global__ __launch_bounds__(192) void fused_kernel(
    const float* __restrict__ seq, const float* __restrict__ pooled,
    const int* __restrict__ tt, const int* __restrict__ wm,
    const int* __restrict__ gids,
    const float* __restrict__ gapW, const float* __restrict__ gapb,
    const float* __restrict__ clsW, const float* __restrict__ clsb,
    float* __restrict__ pmax, float* __restrict__ psum,
    int* __restrict__ pcnt, float* __restrict__ out) {
    const int blk = blockIdx.x;
    const int tid = threadIdx.x;

    __shared__ float sbuf[256];
    __shared__ int s_idx[CHUNK];
    __shared__ unsigned long long s_wmask[2];
    __shared__ int s_misc[2];
    __shared__ int s_last;

    const float4 ninf4 = make_float4(-INFINITY, -INFINITY, -INFINITY, -INFINITY);
    const float4 zero4 = make_float4(0.f, 0.f, 0.f, 0.f);

    if (blk < NB * NCH) {
        // ---------------- text partial ----------------
        const int b = blk / NCH;
        const int ss = blk % NCH;
        const int s0 = ss * CHUNK;

        // evaluate mask (waves 0,1 fully active), ballot per wave
        if (tid < CHUNK) {
            const int s = s0 + tid;
            bool v = (tt[b * NS + s] == 0) && (wm[b * NS + s] != 0);
            unsigned long long m = __ballot(v);
            if ((tid & 63) == 0) s_wmask[tid >> 6] = m;
        }
        __syncthreads();
        // compact valid row indices into s_idx
        if (tid < CHUNK) {
            const int w = tid >> 6, l = tid & 63;
            const unsigned long long m = s_wmask[w];
            if ((m >> l) & 1ull) {
                int pos = (w ? __popcll(s_wmask[0]) : 0) +
                          __popcll(m & ((1ull << l) - 1ull));
                s_idx[pos] = s0 + tid;
            }
        }
        if (tid == 0)
            s_misc[0] = __popcll(s_wmask[0]) + __popcll(s_wmask[1]);
        __syncthreads();
        const int n = s_misc[0];

        const float4* rowbase = (const float4*)(seq + (size_t)b * NS * NH);
        float4 mx = ninf4;
        float4 sm = zero4;
        int i = 0;
        for (; i + 8 <= n; i += 8) {  // 8 independent loads in flight
            const int i0 = s_idx[i],     i1 = s_idx[i + 1];
            const int i2 = s_idx[i + 2], i3 = s_idx[i + 3];
            const int i4 = s_idx[i + 4], i5 = s_idx[i + 5];
            const int i6 = s_idx[i + 6], i7 = s_idx[i + 7];
            float4 v0 = rowbase[(size_t)i0 * NH4 + tid];
            float4 v1 = rowbase[(size_t)i1 * NH4 + tid];
            float4 v2 = rowbase[(size_t)i2 * NH4 + tid];
            float4 v3 = rowbase[(size_t)i3 * NH4 + tid];
            float4 v4 = rowbase[(size_t)i4 * NH4 + tid];
            float4 v5 = rowbase[(size_t)i5 * NH4 + tid];
            float4 v6 = rowbase[(size_t)i6 * NH4 + tid];
            float4 v7 = rowbase[(size_t)i7 * NH4 + tid];
            mx = f4max(mx, f4max(f4max(f4max(v0, v1), f4max(v2, v3)),
                                 f4max(f4max(v4, v5), f4max(v6, v7))));
            sm = f4add(sm, f4add(f4add(f4add(v0, v1), f4add(v2, v3)),
                                 f4add(f4add(v4, v5), f4add(v6, v7))));
        }
        if (i + 4 <= n) {
            const int i0 = s_idx[i],     i1 = s_idx[i + 1];
            const int i2 = s_idx[i + 2], i3 = s_idx[i + 3];
            float4 v0 = rowbase[(size_t)i0 * NH4 + tid];
            float4 v1 = rowbase[(size_t)i1 * NH4 + tid];
            float4 v2 = rowbase[(size_t)i2 * NH4 + tid];
            float4 v3 = rowbase[(size_t)i3 * NH4 + tid];
            mx = f4max(mx, f4max(f4max(v0, v1), f4max(v2, v3)));
            sm = f4add(sm, f4add(f4add(v0, v1), f4add(v2, v3)));
            i += 4;
        }
        if (i + 2 <= n) {
            const int i0 = s_idx[i], i1 = s_idx[i + 1];
            float4 v0 = rowbase[(size_t)i0 * NH4 + tid];
            float4 v1 = rowbase[(size_t)i1 * NH4 + tid];
            mx = f4max(mx, f4max(v0, v1));
            sm = f4add(sm, f4add(v0, v1));
            i += 2;
        }
        if (i < n) {
            float4 v = rowbase[(size_t)s_idx[i] * NH4 + tid];
            mx = f4max(mx, v);
            sm = f4add(sm, v);
        }
        const size_t o = ((size_t)(b * NCH + ss)) * NH4 + tid;
        ((float4*)pmax)[o] = mx;
        ((float4*)psum)[o] = sm;
        if (tid == 0) pcnt[b * NCH + ss] = n;

        // ---- last block of this batch performs the cls reduction ----
        __threadfence();  // release: make pmax/psum/pcnt visible device-wide
        if (tid == 0) {
            const int old = atomicAdd(&g_cnt[b], 1);
            s_last = (old == NCH - 1);
            if (s_last) atomicExch(&g_cnt[b], 0);  // re-arm for next replay
        }
        __syncthreads();
        if (s_last) {
            __threadfence();  // acquire: see all batch partials

            // count: sum of 32 ints (exact in fp32)
            float c = (tid < NCH) ? (float)pcnt[b * NCH + tid] : 0.f;
            const float count = block_reduce_192(c, sbuf);

            const float4* pm4 = (const float4*)pmax;
            const float4* ps4 = (const float4*)psum;
            float4 cmx = ninf4;
            float4 csm = zero4;
#pragma unroll 8
            for (int ch = 0; ch < NCH; ++ch) {
                const size_t oo = ((size_t)(b * NCH + ch)) * NH4 + tid;
                cmx = f4max(cmx, pm4[oo]);
                csm = f4add(csm, ps4[oo]);
            }
            const float4 tmax = f4max(cmx, zero4);
            const float4 tavg = make_float4(csm.x / count, csm.y / count,
                                            csm.z / count, csm.w / count);

            const float4* p4 = (const float4*)(pooled + (size_t)b * NH);
            const float4* w0 = (const float4*)clsW;
            const float4* w1 = (const float4*)(clsW + NH);
            const float4* w2 = (const float4*)(clsW + 2 * NH);
            float part = f4dot(p4[tid], w0[tid]) + f4dot(tmax, w1[tid]) +
                         f4dot(tavg, w2[tid]);
            float total = block_reduce_192(part, sbuf);
            if (tid == 0) out[b * OUTW + 0] = total + clsb[0];
        }
    } else {
        // ---------------- gap score ----------------
        const int bg = blk - NB * NCH;
        const int b = bg >> 4;
        const int g = bg & 15;

        if (tid == 0) s_misc[1] = gids[b * NG + g];
        __syncthreads();
        const int gi = s_misc[1];

        if (tid < 64) {  // wave 0 computes the 31 validity bits
            bool v = false;
            if (tid < WLEN) {
                const int idx = gi - WRAD + tid;
                v = (idx >= 0) && (idx < NS) && (tt[b * NS + idx] == 0) &&
                    (wm[b * NS + idx] != 0);
            }
            unsigned long long m = __ballot(v);
            if (tid == 0) s_wmask[0] = m;
        }
        __syncthreads();
        const unsigned long long vm = s_wmask[0];
        const float count = (float)__popcll(vm);

        const float4* rowbase = (const float4*)(seq + (size_t)b * NS * NH);
        const float4 gv = rowbase[(size_t)gi * NH4 + tid];

        float4 mx = ninf4;
        float4 sm = zero4;
#pragma unroll 8
        for (int j = 0; j < WLEN; ++j) {
            int idx = gi - WRAD + j;
            idx = idx < 0 ? 0 : (idx > NS - 1 ? NS - 1 : idx);
            const float4 v = rowbase[(size_t)idx * NH4 + tid];  // unconditional
            const bool val = (vm >> j) & 1ull;
            // branch-free select (v_cndmask), loads stay pipelined
            mx.x = val ? fmaxf(mx.x, v.x) : mx.x;
            mx.y = val ? fmaxf(mx.y, v.y) : mx.y;
            mx.z = val ? fmaxf(mx.z, v.z) : mx.z;
            mx.w = val ? fmaxf(mx.w, v.w) : mx.w;
            sm.x += val ? v.x : 0.f;
            sm.y += val ? v.y : 0.f;
            sm.z += val ? v.z : 0.f;
            sm.w += val ? v.w : 0.f;
        }
        const float4 wmax = f4max(mx, zero4);
        // plain division: count==0 -> 0/0 = NaN, matching the reference.
        const float4 wavg = make_float4(sm.x / count, sm.y / count,
                                        sm.z / count, sm.w / count);

        const float4* w0 = (const float4*)gapW;
        const float4* w1 = (const float4*)(gapW + NH);
        const float4* w2 = (const float4*)(gapW + 2 * NH);
        float part = f4dot(gv, w0[tid]) + f4dot(wmax, w1[tid]) + f4dot(wavg, w2[tid]);
        float total = block_reduce_192(part, sbuf);
        if (tid == 0) out[b * OUTW + 1 + g] = total + gapb[0];
    }
}

extern "C" void kernel_launch(void* const* d_in, const int* in_sizes, int n_in,
                              void* d_out, int out_size, void* d_ws, size_t ws_size,
                              hipStream_t stream) {
    const float* seq    = (const float*)d_in[0];  // [B,S,H] fp32
    const float* pooled = (const float*)d_in[1];  // [B,H]
    const int*   tt     = (const int*)d_in[2];    // [B,S]
    const int*   wm     = (const int*)d_in[3];    // [B,S]
    const int*   gids   = (const int*)d_in[4];    // [B,G]
    const float* gapW   = (const float*)d_in[5];  // [3H]
    const float* gapb   = (const float*)d_in[6];  // scalar
    const float* clsW   = (const float*)d_in[7];  // [3H]
    const float* clsb   = (const float*)d_in[8];  // scalar
    float* out = (float*)d_out;

    // ws layout: pmax | psum | pcnt  (all written before read within the kernel)
    float* pmax = (float*)d_ws;
    float* psum = pmax + (size_t)NB * NCH * NH;
    int*   pcnt = (int*)(psum + (size_t)NB * NCH * NH);

    fused_kernel<<<NB * NCH + NB * NG, 192, 0, stream>>>(
        seq, pooled, tt, wm, gids, gapW, gapb, clsW, clsb,
        pmax, psum, pcnt, out);
}

// Round 4
// 290.536 us; speedup vs baseline: 1.2332x; 1.2332x over previous
//
#include <hip/hip_runtime.h>
#include <math.h>

#define NB 16
#define NS 4096
#define NH 768
#define NG 16
#define WRAD 15
#define WLEN 31
#define NH4 192     // NH / 4 float4 columns
#define OUTW (1 + NG)
#define NCH 32      // s-chunks per batch
#define CHUNK 128   // NS / NCH

__device__ inline float4 f4max(float4 a, float4 b) {
    return make_float4(fmaxf(a.x, b.x), fmaxf(a.y, b.y), fmaxf(a.z, b.z), fmaxf(a.w, b.w));
}
__device__ inline float4 f4add(float4 a, float4 b) {
    return make_float4(a.x + b.x, a.y + b.y, a.z + b.z, a.w + b.w);
}
__device__ inline float f4dot(float4 a, float4 b) {
    return a.x * b.x + a.y * b.y + a.z * b.z + a.w * b.w;
}

// Block reduce (blockDim.x == 192): pad LDS to 256, power-of-2 tree.
__device__ inline float block_reduce_192(float v, float* sbuf) {
    int tid = threadIdx.x;
    sbuf[tid] = v;
    if (tid < 64) sbuf[192 + tid] = 0.0f;
    __syncthreads();
    for (int off = 128; off > 0; off >>= 1) {
        if (tid < off) sbuf[tid] += sbuf[tid + off];
        __syncthreads();
    }
    float r = sbuf[0];
    __syncthreads();
    return r;
}

// ---------------------------------------------------------------------------
// Fused kernel: blocks [0, NB*NCH) do masked text partials (compacted,
// branch-free inner loop); blocks [NB*NCH, NB*NCH+NB*NG) do gap scores.
// block = 192 threads; thread t owns float4 column t.
// Latency-bound (6 waves/CU from grid size) -> keep 16 loads in flight.
// NO device-scope fences anywhere (R3 lesson: per-block __threadfence on
// gfx950 = L2 writeback x512 blocks, tripled the kernel).
// ---------------------------------------------------------------------------
__global__ __launch_bounds__(192) void fused_kernel(
    const float* __restrict__ seq, const int* __restrict__ tt,
    const int* __restrict__ wm, const int* __restrict__ gids,
    const float* __restrict__ gapW, const float* __restrict__ gapb,
    float* __restrict__ pmax, float* __restrict__ psum,
    int* __restrict__ pcnt, float* __restrict__ out) {
    const int blk = blockIdx.x;
    const int tid = threadIdx.x;

    __shared__ float sbuf[256];
    __shared__ int s_idx[CHUNK];
    __shared__ unsigned long long s_wmask[2];
    __shared__ int s_misc[2];

    const float4 ninf4 = make_float4(-INFINITY, -INFINITY, -INFINITY, -INFINITY);
    const float4 zero4 = make_float4(0.f, 0.f, 0.f, 0.f);

    if (blk < NB * NCH) {
        // ---------------- text partial ----------------
        const int b = blk / NCH;
        const int ss = blk % NCH;
        const int s0 = ss * CHUNK;

        // evaluate mask (waves 0,1 fully active), ballot per wave
        if (tid < CHUNK) {
            const int s = s0 + tid;
            bool v = (tt[b * NS + s] == 0) && (wm[b * NS + s] != 0);
            unsigned long long m = __ballot(v);
            if ((tid & 63) == 0) s_wmask[tid >> 6] = m;
        }
        __syncthreads();
        // compact valid row indices into s_idx
        if (tid < CHUNK) {
            const int w = tid >> 6, l = tid & 63;
            const unsigned long long m = s_wmask[w];
            if ((m >> l) & 1ull) {
                int pos = (w ? __popcll(s_wmask[0]) : 0) +
                          __popcll(m & ((1ull << l) - 1ull));
                s_idx[pos] = s0 + tid;
            }
        }
        if (tid == 0)
            s_misc[0] = __popcll(s_wmask[0]) + __popcll(s_wmask[1]);
        __syncthreads();
        const int n = s_misc[0];

        const float4* rowbase = (const float4*)(seq + (size_t)b * NS * NH);
        float4 mx = ninf4;
        float4 sm = zero4;
        int i = 0;
        for (; i + 16 <= n; i += 16) {  // 16 independent loads in flight
            float4 v0  = rowbase[(size_t)s_idx[i]      * NH4 + tid];
            float4 v1  = rowbase[(size_t)s_idx[i + 1]  * NH4 + tid];
            float4 v2  = rowbase[(size_t)s_idx[i + 2]  * NH4 + tid];
            float4 v3  = rowbase[(size_t)s_idx[i + 3]  * NH4 + tid];
            float4 v4  = rowbase[(size_t)s_idx[i + 4]  * NH4 + tid];
            float4 v5  = rowbase[(size_t)s_idx[i + 5]  * NH4 + tid];
            float4 v6  = rowbase[(size_t)s_idx[i + 6]  * NH4 + tid];
            float4 v7  = rowbase[(size_t)s_idx[i + 7]  * NH4 + tid];
            float4 v8  = rowbase[(size_t)s_idx[i + 8]  * NH4 + tid];
            float4 v9  = rowbase[(size_t)s_idx[i + 9]  * NH4 + tid];
            float4 v10 = rowbase[(size_t)s_idx[i + 10] * NH4 + tid];
            float4 v11 = rowbase[(size_t)s_idx[i + 11] * NH4 + tid];
            float4 v12 = rowbase[(size_t)s_idx[i + 12] * NH4 + tid];
            float4 v13 = rowbase[(size_t)s_idx[i + 13] * NH4 + tid];
            float4 v14 = rowbase[(size_t)s_idx[i + 14] * NH4 + tid];
            float4 v15 = rowbase[(size_t)s_idx[i + 15] * NH4 + tid];
            mx = f4max(mx,
                 f4max(f4max(f4max(f4max(v0, v1), f4max(v2, v3)),
                             f4max(f4max(v4, v5), f4max(v6, v7))),
                       f4max(f4max(f4max(v8, v9), f4max(v10, v11)),
                             f4max(f4max(v12, v13), f4max(v14, v15)))));
            sm = f4add(sm,
                 f4add(f4add(f4add(f4add(v0, v1), f4add(v2, v3)),
                             f4add(f4add(v4, v5), f4add(v6, v7))),
                       f4add(f4add(f4add(v8, v9), f4add(v10, v11)),
                             f4add(f4add(v12, v13), f4add(v14, v15)))));
        }
        if (i + 8 <= n) {
            float4 v0 = rowbase[(size_t)s_idx[i]     * NH4 + tid];
            float4 v1 = rowbase[(size_t)s_idx[i + 1] * NH4 + tid];
            float4 v2 = rowbase[(size_t)s_idx[i + 2] * NH4 + tid];
            float4 v3 = rowbase[(size_t)s_idx[i + 3] * NH4 + tid];
            float4 v4 = rowbase[(size_t)s_idx[i + 4] * NH4 + tid];
            float4 v5 = rowbase[(size_t)s_idx[i + 5] * NH4 + tid];
            float4 v6 = rowbase[(size_t)s_idx[i + 6] * NH4 + tid];
            float4 v7 = rowbase[(size_t)s_idx[i + 7] * NH4 + tid];
            mx = f4max(mx, f4max(f4max(f4max(v0, v1), f4max(v2, v3)),
                                 f4max(f4max(v4, v5), f4max(v6, v7))));
            sm = f4add(sm, f4add(f4add(f4add(v0, v1), f4add(v2, v3)),
                                 f4add(f4add(v4, v5), f4add(v6, v7))));
            i += 8;
        }
        if (i + 4 <= n) {
            float4 v0 = rowbase[(size_t)s_idx[i]     * NH4 + tid];
            float4 v1 = rowbase[(size_t)s_idx[i + 1] * NH4 + tid];
            float4 v2 = rowbase[(size_t)s_idx[i + 2] * NH4 + tid];
            float4 v3 = rowbase[(size_t)s_idx[i + 3] * NH4 + tid];
            mx = f4max(mx, f4max(f4max(v0, v1), f4max(v2, v3)));
            sm = f4add(sm, f4add(f4add(v0, v1), f4add(v2, v3)));
            i += 4;
        }
        if (i + 2 <= n) {
            float4 v0 = rowbase[(size_t)s_idx[i]     * NH4 + tid];
            float4 v1 = rowbase[(size_t)s_idx[i + 1] * NH4 + tid];
            mx = f4max(mx, f4max(v0, v1));
            sm = f4add(sm, f4add(v0, v1));
            i += 2;
        }
        if (i < n) {
            float4 v = rowbase[(size_t)s_idx[i] * NH4 + tid];
            mx = f4max(mx, v);
            sm = f4add(sm, v);
        }
        const size_t o = ((size_t)(b * NCH + ss)) * NH4 + tid;
        ((float4*)pmax)[o] = mx;
        ((float4*)psum)[o] = sm;
        if (tid == 0) pcnt[b * NCH + ss] = n;
    } else {
        // ---------------- gap score ----------------
        const int bg = blk - NB * NCH;
        const int b = bg >> 4;
        const int g = bg & 15;

        if (tid == 0) s_misc[1] = gids[b * NG + g];
        __syncthreads();
        const int gi = s_misc[1];

        if (tid < 64) {  // wave 0 computes the 31 validity bits
            bool v = false;
            if (tid < WLEN) {
                const int idx = gi - WRAD + tid;
                v = (idx >= 0) && (idx < NS) && (tt[b * NS + idx] == 0) &&
                    (wm[b * NS + idx] != 0);
            }
            unsigned long long m = __ballot(v);
            if (tid == 0) s_wmask[0] = m;
        }
        __syncthreads();
        const unsigned long long vm = s_wmask[0];
        const float count = (float)__popcll(vm);

        const float4* rowbase = (const float4*)(seq + (size_t)b * NS * NH);
        const float4 gv = rowbase[(size_t)gi * NH4 + tid];

        float4 mx = ninf4;
        float4 sm = zero4;
#pragma unroll 8
        for (int j = 0; j < WLEN; ++j) {
            int idx = gi - WRAD + j;
            idx = idx < 0 ? 0 : (idx > NS - 1 ? NS - 1 : idx);
            const float4 v = rowbase[(size_t)idx * NH4 + tid];  // unconditional
            const bool val = (vm >> j) & 1ull;
            // branch-free select (v_cndmask), loads stay pipelined
            mx.x = val ? fmaxf(mx.x, v.x) : mx.x;
            mx.y = val ? fmaxf(mx.y, v.y) : mx.y;
            mx.z = val ? fmaxf(mx.z, v.z) : mx.z;
            mx.w = val ? fmaxf(mx.w, v.w) : mx.w;
            sm.x += val ? v.x : 0.f;
            sm.y += val ? v.y : 0.f;
            sm.z += val ? v.z : 0.f;
            sm.w += val ? v.w : 0.f;
        }
        const float4 wmax = f4max(mx, zero4);
        // plain division: count==0 -> 0/0 = NaN, matching the reference.
        const float4 wavg = make_float4(sm.x / count, sm.y / count,
                                        sm.z / count, sm.w / count);

        const float4* w0 = (const float4*)gapW;
        const float4* w1 = (const float4*)(gapW + NH);
        const float4* w2 = (const float4*)(gapW + 2 * NH);
        float part = f4dot(gv, w0[tid]) + f4dot(wmax, w1[tid]) + f4dot(wavg, w2[tid]);
        float total = block_reduce_192(part, sbuf);
        if (tid == 0) out[b * OUTW + 1 + g] = total + gapb[0];
    }
}

// ---------------------------------------------------------------------------
// cls kernel: one block per b, combines NCH partials + counts, fused dot.
// ---------------------------------------------------------------------------
__global__ __launch_bounds__(192) void cls_kernel(
    const float* __restrict__ pooled, const float* __restrict__ pmax,
    const float* __restrict__ psum, const int* __restrict__ pcnt,
    const float* __restrict__ clsW, const float* __restrict__ clsb,
    float* __restrict__ out) {
    const int b = blockIdx.x;
    const int tid = threadIdx.x;
    __shared__ float sbuf[256];

    float c = (tid < NCH) ? (float)pcnt[b * NCH + tid] : 0.f;
    const float count = block_reduce_192(c, sbuf);

    const float4* pm4 = (const float4*)pmax;
    const float4* ps4 = (const float4*)psum;
    float4 mx = make_float4(-INFINITY, -INFINITY, -INFINITY, -INFINITY);
    float4 sm = make_float4(0.f, 0.f, 0.f, 0.f);
#pragma unroll 8
    for (int ch = 0; ch < NCH; ++ch) {
        const size_t o = ((size_t)(b * NCH + ch)) * NH4 + tid;
        mx = f4max(mx, pm4[o]);
        sm = f4add(sm, ps4[o]);
    }
    const float4 zero4 = make_float4(0.f, 0.f, 0.f, 0.f);
    const float4 tmax = f4max(mx, zero4);
    const float4 tavg = make_float4(sm.x / count, sm.y / count,
                                    sm.z / count, sm.w / count);

    const float4* p4 = (const float4*)(pooled + (size_t)b * NH);
    const float4* w0 = (const float4*)clsW;
    const float4* w1 = (const float4*)(clsW + NH);
    const float4* w2 = (const float4*)(clsW + 2 * NH);
    float part = f4dot(p4[tid], w0[tid]) + f4dot(tmax, w1[tid]) + f4dot(tavg, w2[tid]);
    float total = block_reduce_192(part, sbuf);
    if (tid == 0) out[b * OUTW + 0] = total + clsb[0];
}

extern "C" void kernel_launch(void* const* d_in, const int* in_sizes, int n_in,
                              void* d_out, int out_size, void* d_ws, size_t ws_size,
                              hipStream_t stream) {
    const float* seq    = (const float*)d_in[0];  // [B,S,H] fp32
    const float* pooled = (const float*)d_in[1];  // [B,H]
    const int*   tt     = (const int*)d_in[2];    // [B,S]
    const int*   wm     = (const int*)d_in[3];    // [B,S]
    const int*   gids   = (const int*)d_in[4];    // [B,G]
    const float* gapW   = (const float*)d_in[5];  // [3H]
    const float* gapb   = (const float*)d_in[6];  // scalar
    const float* clsW   = (const float*)d_in[7];  // [3H]
    const float* clsb   = (const float*)d_in[8];  // scalar
    float* out = (float*)d_out;

    // ws layout: pmax | psum | pcnt  (all written by fused_kernel before read)
    float* pmax = (float*)d_ws;
    float* psum = pmax + (size_t)NB * NCH * NH;
    int*   pcnt = (int*)(psum + (size_t)NB * NCH * NH);

    fused_kernel<<<NB * NCH + NB * NG, 192, 0, stream>>>(
        seq, tt, wm, gids, gapW, gapb, pmax, psum, pcnt, out);
    cls_kernel<<<NB, 192, 0, stream>>>(pooled, pmax, psum, pcnt, clsW, clsb, out);
}